// Round 1
// baseline (298.126 us; speedup 1.0000x reference)
//
#include <hip/hip_runtime.h>
#include <stdint.h>

#define BATCH 8
#define NC 80
#define NA1 8112
#define NA2 2028
#define NA3 507
#define NTOT 10647
#define KSEL 256
#define MAXPC 100
#define MAXTOT 100
#define NEGV -1000000000.0f
#define SCTHR 0.3f
#define IOUTHR 0.5f
#define M2 (NC * KSEL)   /* 20480 per image */
#define MAXCAND 8000     /* hard bound: <=100 kept per class * 80 classes */

// static device scratch (no dependence on ws_size); fully rewritten every launch
__device__ float g_s[BATCH * NC * KSEL];
__device__ int   g_n[BATCH * NC * KSEL];

__device__ __forceinline__ unsigned okey(float f) {
  unsigned u = __float_as_uint(f);
  return u ^ ((unsigned)((int)u >> 31) | 0x80000000u);  // orderable: bigger uint == bigger float
}
__device__ __forceinline__ float inv_okey(unsigned k) {
  unsigned u = (k & 0x80000000u) ? (k ^ 0x80000000u) : ~k;
  return __uint_as_float(u);
}

// Find threshold T = kwant-th largest key among keys[0..cnt); need_out = #elems == T to take.
// Requires blockDim.x == 256; hist/suf are 256-entry LDS arrays, s_sel 2-entry LDS.
__device__ void radix_select(const unsigned* keys, int cnt, unsigned kwant,
                             unsigned* hist, unsigned* suf, unsigned* s_sel,
                             unsigned& T_out, unsigned& need_out)
{
  const int tid = threadIdx.x;
  unsigned need = kwant, prefix = 0;
  for (int shift = 24; shift >= 0; shift -= 8) {
    hist[tid] = 0;
    __syncthreads();
    unsigned maskhi = (shift == 24) ? 0u : (0xFFFFFFFFu << (shift + 8));
    for (int n = tid; n < cnt; n += 256) {
      unsigned k = keys[n];
      if ((k & maskhi) == prefix) atomicAdd(&hist[(k >> shift) & 255u], 1u);
    }
    __syncthreads();
    suf[tid] = hist[tid];
    __syncthreads();
    for (int off = 1; off < 256; off <<= 1) {   // inclusive suffix sum
      unsigned v = suf[tid] + ((tid + off < 256) ? suf[tid + off] : 0u);
      __syncthreads();
      suf[tid] = v;
      __syncthreads();
    }
    unsigned mys = suf[tid];
    unsigned nxt = (tid == 255) ? 0u : suf[tid + 1];
    if (mys >= need && nxt < need) {            // exactly one thread hits this
      s_sel[0] = prefix | ((unsigned)tid << shift);
      s_sel[1] = need - nxt;
    }
    __syncthreads();
    prefix = s_sel[0];
    need = s_sel[1];
    __syncthreads();
  }
  T_out = prefix;
  need_out = need;
}

__global__ __launch_bounds__(256)
void nms_per_class(const float* __restrict__ b1, const float* __restrict__ c1, const float* __restrict__ p1,
                   const float* __restrict__ b2, const float* __restrict__ c2, const float* __restrict__ p2,
                   const float* __restrict__ b3, const float* __restrict__ c3, const float* __restrict__ p3)
{
  const int tid = threadIdx.x;
  const int b = blockIdx.x / NC;
  const int c = blockIdx.x % NC;

  __shared__ unsigned sarr[NTOT];          // 42588 B
  __shared__ unsigned hist[256];
  __shared__ unsigned suf[256];
  __shared__ unsigned s_sel[2];
  __shared__ int s_cgt, s_ceq;
  __shared__ unsigned long long cand[KSEL];
  __shared__ float4 cbox[KSEL];
  __shared__ float csc[KSEL];
  __shared__ unsigned char keepf[KSEL];
  __shared__ unsigned char keptf[KSEL];

  // scores -> orderable keys in LDS (all scores >= 0)
  for (int n = tid; n < NTOT; n += 256) {
    float cf, pv;
    if (n < NA1)            { int l = n;             cf = c1[b * NA1 + l]; pv = p1[(size_t)(b * NA1 + l) * NC + c]; }
    else if (n < NA1 + NA2) { int l = n - NA1;       cf = c2[b * NA2 + l]; pv = p2[(size_t)(b * NA2 + l) * NC + c]; }
    else                    { int l = n - NA1 - NA2; cf = c3[b * NA3 + l]; pv = p3[(size_t)(b * NA3 + l) * NC + c]; }
    sarr[n] = okey(cf * pv);
  }
  __syncthreads();

  unsigned T, need;
  radix_select(sarr, NTOT, KSEL, hist, suf, s_sel, T, need);

  if (tid == 0) { s_cgt = 0; s_ceq = 0; }
  __syncthreads();
  const int ngt = KSEL - (int)need;        // exact count of keys > T
  for (int n = tid; n < NTOT; n += 256) {
    unsigned k = sarr[n];
    if (k > T) {
      int p = atomicAdd(&s_cgt, 1);
      cand[p] = ((unsigned long long)k << 32) | (unsigned)(~n);
    } else if (k == T) {
      int p = atomicAdd(&s_ceq, 1);
      if (p < (int)need) cand[ngt + p] = ((unsigned long long)k << 32) | (unsigned)(~n);
    }
  }
  __syncthreads();

  // bitonic sort 256, descending by (key, ~n) => score desc, index asc on ties
  for (int kk = 2; kk <= KSEL; kk <<= 1) {
    for (int j = kk >> 1; j > 0; j >>= 1) {
      int ixj = tid ^ j;
      if (ixj > tid) {
        unsigned long long a = cand[tid], cc = cand[ixj];
        if (((tid & kk) == 0) ? (a < cc) : (a > cc)) { cand[tid] = cc; cand[ixj] = a; }
      }
      __syncthreads();
    }
  }

  int myn;
  {
    unsigned long long ck = cand[tid];
    unsigned k = (unsigned)(ck >> 32);
    myn = (int)(~(unsigned)ck);
    csc[tid] = inv_okey(k);
    const float* bp;
    if (myn < NA1)            bp = b1 + (size_t)(b * NA1 + myn) * 4;
    else if (myn < NA1 + NA2) bp = b2 + (size_t)(b * NA2 + (myn - NA1)) * 4;
    else                      bp = b3 + (size_t)(b * NA3 + (myn - NA1 - NA2)) * 4;
    cbox[tid] = make_float4(bp[0], bp[1], bp[2], bp[3]);  // (y1,x1,y2,x2)
    keepf[tid] = 1;
  }
  __syncthreads();

  // greedy NMS: thread j owns candidate j
  const float4 mb = cbox[tid];
  const float myarea = (mb.z - mb.x) * (mb.w - mb.y);
  for (int i = 0; i < KSEL; ++i) {
    const bool cur = (keepf[i] != 0) && (csc[i] > SCTHR);
    if (tid == i) keptf[i] = cur ? 1 : 0;
    if (cur && tid > i) {
      float4 bi = cbox[i];
      float ia = (bi.z - bi.x) * (bi.w - bi.y);
      float iy = fmaxf(fminf(bi.z, mb.z) - fmaxf(bi.x, mb.x), 0.0f);
      float ix = fmaxf(fminf(bi.w, mb.w) - fmaxf(bi.y, mb.y), 0.0f);
      float inter = iy * ix;
      float uni = ia + myarea - inter;
      float iou = (uni > 0.0f) ? inter / uni : 0.0f;
      if (iou > IOUTHR) keepf[tid] = 0;
    }
    __syncthreads();
  }

  if (tid == 0) {  // cap at MAXPC kept (cumsum <= 100)
    int run = 0;
    for (int i = 0; i < KSEL; ++i)
      if (keptf[i]) { if (++run > MAXPC) keptf[i] = 0; }
  }
  __syncthreads();

  const size_t base = ((size_t)b * NC + c) * KSEL + tid;
  g_s[base] = keptf[tid] ? csc[tid] : NEGV;
  g_n[base] = myn;
}

__global__ __launch_bounds__(256)
void nms_final(const float* __restrict__ b1, const float* __restrict__ b2, const float* __restrict__ b3,
               float* __restrict__ out)
{
  const int tid = threadIdx.x;
  const int b = blockIdx.x;

  __shared__ unsigned lk[MAXCAND];         // 32000 B
  __shared__ unsigned short lfi[MAXCAND];  // 16000 B
  __shared__ unsigned hist[256];
  __shared__ unsigned suf[256];
  __shared__ unsigned s_sel[2];
  __shared__ int s_cnt, s_cgt, s_ceq, s_nv;
  __shared__ unsigned long long cand[128];

  if (tid == 0) s_cnt = 0;
  __syncthreads();

  // wave-aggregated compaction of valid (> SCTHR) entries; all else is NEGV
  const float* s = g_s + (size_t)b * M2;
  for (int base2 = 0; base2 < M2; base2 += 256) {   // M2 % 256 == 0
    int fi = base2 + tid;
    float sc = s[fi];
    bool pred = sc > SCTHR;
    unsigned long long mask = __ballot(pred);
    if (mask != 0ULL) {
      int lane = tid & 63;
      int ldr = __ffsll(mask) - 1;
      int wb = 0;
      if (lane == ldr) wb = atomicAdd(&s_cnt, __popcll(mask));
      wb = __shfl(wb, ldr, 64);
      if (pred) {
        int pos = wb + __popcll(mask & ((1ULL << lane) - 1ULL));
        lk[pos] = okey(sc);
        lfi[pos] = (unsigned short)fi;
      }
    }
  }
  __syncthreads();
  const int cnt = s_cnt;

  if (tid < 128) cand[tid] = 0ULL;
  __syncthreads();

  if (cnt <= MAXTOT) {          // everything qualifies; pads stay 0
    if (tid < cnt)
      cand[tid] = ((unsigned long long)lk[tid] << 16) | (unsigned)((~lfi[tid]) & 0xFFFF);
    __syncthreads();
  } else {
    unsigned T, need;
    radix_select(lk, cnt, MAXTOT, hist, suf, s_sel, T, need);
    if (tid == 0) { s_cgt = 0; s_ceq = 0; }
    __syncthreads();
    const int ngt = MAXTOT - (int)need;
    for (int i = tid; i < cnt; i += 256) {
      unsigned k = lk[i];
      if (k > T) {
        int p = atomicAdd(&s_cgt, 1);
        cand[p] = ((unsigned long long)k << 16) | (unsigned)((~lfi[i]) & 0xFFFF);
      } else if (k == T) {
        int p = atomicAdd(&s_ceq, 1);
        if (p < (int)need) cand[ngt + p] = ((unsigned long long)k << 16) | (unsigned)((~lfi[i]) & 0xFFFF);
      }
    }
    __syncthreads();
  }

  // sort 128 descending by (key, ~fi); zero pads sink to the end
  for (int kk = 2; kk <= 128; kk <<= 1) {
    for (int j = kk >> 1; j > 0; j >>= 1) {
      if (tid < 128) {
        int ixj = tid ^ j;
        if (ixj > tid) {
          unsigned long long a = cand[tid], cc = cand[ixj];
          if (((tid & kk) == 0) ? (a < cc) : (a > cc)) { cand[tid] = cc; cand[ixj] = a; }
        }
      }
      __syncthreads();
    }
  }

  if (tid == 0) s_nv = 0;
  __syncthreads();

  if (tid < MAXTOT) {
    unsigned long long ck = cand[tid];
    float o0 = 0.f, o1 = 0.f, o2 = 0.f, o3 = 0.f, osc = 0.f, ocl = 0.f;
    if (ck != 0ULL) {
      unsigned k = (unsigned)(ck >> 16);
      int fi = (int)((~(unsigned)ck) & 0xFFFFu);
      float sc = inv_okey(k);
      if (sc > SCTHR) {
        int cls = fi >> 8;                       // fi / KSEL
        int n = g_n[(size_t)b * M2 + fi];
        const float* bp;
        if (n < NA1)            bp = b1 + (size_t)(b * NA1 + n) * 4;
        else if (n < NA1 + NA2) bp = b2 + (size_t)(b * NA2 + (n - NA1)) * 4;
        else                    bp = b3 + (size_t)(b * NA3 + (n - NA1 - NA2)) * 4;
        o0 = fminf(fmaxf(bp[0], 0.0f), 1.0f);
        o1 = fminf(fmaxf(bp[1], 0.0f), 1.0f);
        o2 = fminf(fmaxf(bp[2], 0.0f), 1.0f);
        o3 = fminf(fmaxf(bp[3], 0.0f), 1.0f);
        osc = sc;
        ocl = (float)cls;
        atomicAdd(&s_nv, 1);
      }
    }
    int oi = b * MAXTOT + tid;
    out[(size_t)oi * 4 + 0] = o0;
    out[(size_t)oi * 4 + 1] = o1;
    out[(size_t)oi * 4 + 2] = o2;
    out[(size_t)oi * 4 + 3] = o3;
    out[BATCH * MAXTOT * 4 + oi] = osc;   // scores at 3200
    out[BATCH * MAXTOT * 5 + oi] = ocl;   // classes at 4000
  }
  __syncthreads();
  if (tid == 0) out[BATCH * MAXTOT * 6 + b] = (float)s_nv;  // nvalid at 4800
}

extern "C" void kernel_launch(void* const* d_in, const int* in_sizes, int n_in,
                              void* d_out, int out_size, void* d_ws, size_t ws_size,
                              hipStream_t stream) {
  const float* b1 = (const float*)d_in[0];
  const float* c1 = (const float*)d_in[1];
  const float* p1 = (const float*)d_in[2];
  const float* b2 = (const float*)d_in[3];
  const float* c2 = (const float*)d_in[4];
  const float* p2 = (const float*)d_in[5];
  const float* b3 = (const float*)d_in[6];
  const float* c3 = (const float*)d_in[7];
  const float* p3 = (const float*)d_in[8];
  (void)in_sizes; (void)n_in; (void)out_size; (void)d_ws; (void)ws_size;

  nms_per_class<<<dim3(BATCH * NC), dim3(256), 0, stream>>>(b1, c1, p1, b2, c2, p2, b3, c3, p3);
  nms_final<<<dim3(BATCH), dim3(256), 0, stream>>>(b1, b2, b3, (float*)d_out);
}